// Round 3
// baseline (309.475 us; speedup 1.0000x reference)
//
#include <hip/hip_runtime.h>

// 9x9 box-sum (R=4), zero-padded, 128 fp32 planes of 512x512.
// R3: one wave covers a FULL 512-wide row: 64 lanes x 8 cols. Each thread loads
// only its own two float4s; the neighbor words needed for the horizontal 9-sum
// come from adjacent lanes via DPP wave shifts (WAVE_SHR1/WAVE_SHL1, zero fill).
// This cuts vmem load instructions 3x per row-step vs R0's 3-overlapping-loads
// scheme. Evidence: R0/R1/R2 runtimes scale with rows-loaded (not occupancy,
// not HBM bytes) => vmem-instruction/L1-transaction bound.
// DPP zero boundary fill == the image's zero padding at cols -4..-1 / 512..515.

#define W   512
#define RR  16          // output rows per wave strip
#define NSTRIP (W / RR) // 32

__device__ __forceinline__ float4 ld4(const float* p) { return *(const float4*)p; }
__device__ __forceinline__ float4 add4(float4 a, float4 b) {
    return make_float4(a.x + b.x, a.y + b.y, a.z + b.z, a.w + b.w);
}
__device__ __forceinline__ float4 sub4(float4 a, float4 b) {
    return make_float4(a.x - b.x, a.y - b.y, a.z - b.z, a.w - b.w);
}

// DPP wave-wide lane shifts, zero fill at the boundary lane (gfx9-lineage ctrl).
__device__ __forceinline__ float lane_shr1(float x) {   // lane i <- lane i-1; lane 0 <- 0
    return __int_as_float(__builtin_amdgcn_update_dpp(
        0, __float_as_int(x), 0x138 /*WAVE_SHR1*/, 0xF, 0xF, true));
}
__device__ __forceinline__ float lane_shl1(float x) {   // lane i <- lane i+1; lane 63 <- 0
    return __int_as_float(__builtin_amdgcn_update_dpp(
        0, __float_as_int(x), 0x130 /*WAVE_SHL1*/, 0xF, 0xF, true));
}
__device__ __forceinline__ float4 lane_shr1_4(float4 v) {
    return make_float4(lane_shr1(v.x), lane_shr1(v.y), lane_shr1(v.z), lane_shr1(v.w));
}
__device__ __forceinline__ float4 lane_shl1_4(float4 v) {
    return make_float4(lane_shl1(v.x), lane_shl1(v.y), lane_shl1(v.z), lane_shl1(v.w));
}

__global__ __launch_bounds__(256, 4) void boxfilter9(const float* __restrict__ in,
                                                     float* __restrict__ out) {
    const int t     = threadIdx.x;
    const int l     = t & 63;                       // lane
    const int wid   = t >> 6;                       // wave in block
    const int unit  = blockIdx.x * 4 + wid;         // img*NSTRIP + strip (wave-uniform)
    const int img   = unit >> 5;                    // /NSTRIP
    const int strip = unit & (NSTRIP - 1);

    const float* __restrict__ inp  = in  + (size_t)img * W * W;
    float* __restrict__       outp = out + (size_t)img * W * W;
    const int y0 = strip * RR;
    const int c0 = l << 3;                          // 8 cols per lane

    // horizontal 9-sums for this lane's 8 cols of input row y (zero pad outside)
    auto compute_h = [&](int y, float4& h0, float4& h1) {
        if ((unsigned)y < W) {                      // wave-uniform branch
            const float* row = inp + y * W + c0;
            float4 lo = ld4(row);                   // cols c0  .. c0+3
            float4 hi = ld4(row + 4);               // cols c0+4.. c0+7
            float4 ap = lane_shr1_4(hi);            // cols c0-4.. c0-1 (0 at edge)
            float4 an = lane_shl1_4(lo);            // cols c0+8.. c0+11 (0 at edge)
            float sa = (ap.x + ap.y) + (ap.z + ap.w);
            float sl = (lo.x + lo.y) + (lo.z + lo.w);
            h0.x = (sa + sl) + hi.x;                // cols c0-4 .. c0+4
            h0.y = h0.x - ap.x + hi.y;
            h0.z = h0.y - ap.y + hi.z;
            h0.w = h0.z - ap.z + hi.w;
            h1.x = h0.w - ap.w + an.x;              // cols c0   .. c0+8
            h1.y = h1.x - lo.x + an.y;
            h1.z = h1.y - lo.y + an.z;
            h1.w = h1.z - lo.z + an.w;
        } else {
            h0 = make_float4(0, 0, 0, 0);
            h1 = make_float4(0, 0, 0, 0);
        }
    };

    // init: ring[0..7] = h(y0-4 .. y0+3), vsum = their sum (8 rows of the window)
    float4 ring0[9], ring1[9];
    float4 vs0 = make_float4(0, 0, 0, 0), vs1 = make_float4(0, 0, 0, 0);
    #pragma unroll
    for (int k = 0; k < 8; ++k) {
        compute_h(y0 - 4 + k, ring0[k], ring1[k]);
        vs0 = add4(vs0, ring0[k]);
        vs1 = add4(vs1, ring1[k]);
    }

    // RR output rows; full unroll -> static ring indices, pipelined loads
    #pragma unroll
    for (int i = 0; i < RR; ++i) {
        float4 hn0, hn1;
        compute_h(y0 + 4 + i, hn0, hn1);            // bottom row of window
        float4 o0 = add4(vs0, hn0);                 // 9-row totals
        float4 o1 = add4(vs1, hn1);
        float* orow = outp + (size_t)(y0 + i) * W + c0;
        *(float4*)(orow)     = o0;
        *(float4*)(orow + 4) = o1;
        vs0 = sub4(o0, ring0[i % 9]);               // drop top row for next step
        vs1 = sub4(o1, ring1[i % 9]);
        ring0[(i + 8) % 9] = hn0;
        ring1[(i + 8) % 9] = hn1;
    }
}

extern "C" void kernel_launch(void* const* d_in, const int* in_sizes, int n_in,
                              void* d_out, int out_size, void* d_ws, size_t ws_size,
                              hipStream_t stream) {
    const float* x = (const float*)d_in[0];
    float* y = (float*)d_out;
    // 128 images x 32 strips = 4096 wave-units, 4 per 256-thread block
    dim3 grid(128 * NSTRIP / 4);
    dim3 block(256);
    boxfilter9<<<grid, block, 0, stream>>>(x, y);
}

// Round 4
// 254.779 us; speedup vs baseline: 1.2147x; 1.2147x over previous
//
#include <hip/hip_runtime.h>

// 9x9 box-sum (R=4), zero-padded, 128 fp32 planes of 512x512.
// R4 = R3 structure (one wave per full 512-wide row, 8 cols/lane, DPP lane
// shifts for horizontal neighbors, zero-fill == image padding) with the spill
// fixed: __launch_bounds__(256, 2). R3's (256,4) made the allocator's pressure
// heuristic bail to the 64-VGPR step and spill both rings to scratch
// (WRITE_SIZE 131MB -> 328MB, dur 154us). Natural need is ~110 VGPRs; at that
// size HW still fits 4 waves/SIMD, matching the grid (4096 waves / 1024 SIMDs).

#define W   512
#define RR  16          // output rows per wave strip
#define NSTRIP (W / RR) // 32

__device__ __forceinline__ float4 ld4(const float* p) { return *(const float4*)p; }
__device__ __forceinline__ float4 add4(float4 a, float4 b) {
    return make_float4(a.x + b.x, a.y + b.y, a.z + b.z, a.w + b.w);
}
__device__ __forceinline__ float4 sub4(float4 a, float4 b) {
    return make_float4(a.x - b.x, a.y - b.y, a.z - b.z, a.w - b.w);
}

// DPP wave-wide lane shifts, zero fill at the boundary lane.
__device__ __forceinline__ float lane_shr1(float x) {   // lane i <- lane i-1; lane 0 <- 0
    return __int_as_float(__builtin_amdgcn_update_dpp(
        0, __float_as_int(x), 0x138 /*WAVE_SHR1*/, 0xF, 0xF, true));
}
__device__ __forceinline__ float lane_shl1(float x) {   // lane i <- lane i+1; lane 63 <- 0
    return __int_as_float(__builtin_amdgcn_update_dpp(
        0, __float_as_int(x), 0x130 /*WAVE_SHL1*/, 0xF, 0xF, true));
}
__device__ __forceinline__ float4 lane_shr1_4(float4 v) {
    return make_float4(lane_shr1(v.x), lane_shr1(v.y), lane_shr1(v.z), lane_shr1(v.w));
}
__device__ __forceinline__ float4 lane_shl1_4(float4 v) {
    return make_float4(lane_shl1(v.x), lane_shl1(v.y), lane_shl1(v.z), lane_shl1(v.w));
}

__global__ __launch_bounds__(256, 2) void boxfilter9(const float* __restrict__ in,
                                                     float* __restrict__ out) {
    const int t     = threadIdx.x;
    const int l     = t & 63;                       // lane
    const int wid   = t >> 6;                       // wave in block
    const int unit  = blockIdx.x * 4 + wid;         // img*NSTRIP + strip (wave-uniform)
    const int img   = unit >> 5;                    // /NSTRIP
    const int strip = unit & (NSTRIP - 1);

    const float* __restrict__ inp  = in  + (size_t)img * W * W;
    float* __restrict__       outp = out + (size_t)img * W * W;
    const int y0 = strip * RR;
    const int c0 = l << 3;                          // 8 cols per lane

    // horizontal 9-sums for this lane's 8 cols of input row y (zero pad outside)
    auto compute_h = [&](int y, float4& h0, float4& h1) {
        if ((unsigned)y < W) {                      // wave-uniform branch
            const float* row = inp + y * W + c0;
            float4 lo = ld4(row);                   // cols c0  .. c0+3
            float4 hi = ld4(row + 4);               // cols c0+4.. c0+7
            float4 ap = lane_shr1_4(hi);            // cols c0-4.. c0-1 (0 at edge)
            float4 an = lane_shl1_4(lo);            // cols c0+8.. c0+11 (0 at edge)
            float sa = (ap.x + ap.y) + (ap.z + ap.w);
            float sl = (lo.x + lo.y) + (lo.z + lo.w);
            h0.x = (sa + sl) + hi.x;                // cols c0-4 .. c0+4
            h0.y = h0.x - ap.x + hi.y;
            h0.z = h0.y - ap.y + hi.z;
            h0.w = h0.z - ap.z + hi.w;
            h1.x = h0.w - ap.w + an.x;              // cols c0   .. c0+8
            h1.y = h1.x - lo.x + an.y;
            h1.z = h1.y - lo.y + an.z;
            h1.w = h1.z - lo.z + an.w;
        } else {
            h0 = make_float4(0, 0, 0, 0);
            h1 = make_float4(0, 0, 0, 0);
        }
    };

    // init: ring[0..7] = h(y0-4 .. y0+3), vsum = their sum (8 rows of the window)
    float4 ring0[9], ring1[9];
    float4 vs0 = make_float4(0, 0, 0, 0), vs1 = make_float4(0, 0, 0, 0);
    #pragma unroll
    for (int k = 0; k < 8; ++k) {
        compute_h(y0 - 4 + k, ring0[k], ring1[k]);
        vs0 = add4(vs0, ring0[k]);
        vs1 = add4(vs1, ring1[k]);
    }

    // RR output rows; full unroll -> static ring indices, pipelined loads
    #pragma unroll
    for (int i = 0; i < RR; ++i) {
        float4 hn0, hn1;
        compute_h(y0 + 4 + i, hn0, hn1);            // bottom row of window
        float4 o0 = add4(vs0, hn0);                 // 9-row totals
        float4 o1 = add4(vs1, hn1);
        float* orow = outp + (size_t)(y0 + i) * W + c0;
        *(float4*)(orow)     = o0;
        *(float4*)(orow + 4) = o1;
        vs0 = sub4(o0, ring0[i % 9]);               // drop top row for next step
        vs1 = sub4(o1, ring1[i % 9]);
        ring0[(i + 8) % 9] = hn0;
        ring1[(i + 8) % 9] = hn1;
    }
}

extern "C" void kernel_launch(void* const* d_in, const int* in_sizes, int n_in,
                              void* d_out, int out_size, void* d_ws, size_t ws_size,
                              hipStream_t stream) {
    const float* x = (const float*)d_in[0];
    float* y = (float*)d_out;
    // 128 images x 32 strips = 4096 wave-units, 4 per 256-thread block
    dim3 grid(128 * NSTRIP / 4);
    dim3 block(256);
    boxfilter9<<<grid, block, 0, stream>>>(x, y);
}

// Round 6
// 237.666 us; speedup vs baseline: 1.3021x; 1.0720x over previous
//
#include <hip/hip_runtime.h>

// 9x9 box-sum (R=4), zero-padded, 128 fp32 planes of 512x512.
// R6 = R5 with the compile fix: __builtin_nontemporal_store needs a clang
// ext_vector pointer, not HIP's float4 class. Everything else unchanged.
//
// R5 design notes:
// - lane l owns TWO CONTIGUOUS 4-col groups: A = cols 4l..4l+3, B = 256+4l..+3
//   -> every global load/store is a dense contiguous 1KB per wave instruction
//   (R4's 8-col-blocked mapping made stride-32B half-density stores).
// - horizontal 9-sum via DPP wave shifts (zero bound_ctrl == image edge pad),
//   A<->B seams patched with readlane broadcasts + per-lane selects.
// - branch-free body (clamped row + 0/1 mask) -> one basic block, loads can
//   pipeline rows ahead (R0-R4: ~1290 cy/row-step = exposed L2/L3 latency).
// - ring of 8: out = vsum8 + h_new; vsum8' = out - h_old.
// - nontemporal output stores: output never re-read; keep 134MB input
//   L3-resident (in+out > 256MB L3 was thrashing -> ~95MB refetch/dispatch).

#define W   512
#define RR  16          // output rows per wave strip
#define NSTRIP (W / RR) // 32

typedef float vfloat4 __attribute__((ext_vector_type(4)));

__device__ __forceinline__ float4 ld4(const float* p) { return *(const float4*)p; }
__device__ __forceinline__ float4 add4(float4 a, float4 b) {
    return make_float4(a.x + b.x, a.y + b.y, a.z + b.z, a.w + b.w);
}
__device__ __forceinline__ float4 sub4(float4 a, float4 b) {
    return make_float4(a.x - b.x, a.y - b.y, a.z - b.z, a.w - b.w);
}
__device__ __forceinline__ float4 mul4s(float4 a, float m) {
    return make_float4(a.x * m, a.y * m, a.z * m, a.w * m);
}
__device__ __forceinline__ void st4_nt(float* p, float4 v) {
    vfloat4 q = { v.x, v.y, v.z, v.w };
    __builtin_nontemporal_store(q, (vfloat4*)p);
}

// DPP wave-wide lane shifts, zero fill at the boundary lane.
__device__ __forceinline__ float lane_shr1(float x) {   // lane i <- lane i-1; lane 0 <- 0
    return __int_as_float(__builtin_amdgcn_update_dpp(
        0, __float_as_int(x), 0x138 /*WAVE_SHR1*/, 0xF, 0xF, true));
}
__device__ __forceinline__ float lane_shl1(float x) {   // lane i <- lane i+1; lane 63 <- 0
    return __int_as_float(__builtin_amdgcn_update_dpp(
        0, __float_as_int(x), 0x130 /*WAVE_SHL1*/, 0xF, 0xF, true));
}
__device__ __forceinline__ float4 lane_shr1_4(float4 v) {
    return make_float4(lane_shr1(v.x), lane_shr1(v.y), lane_shr1(v.z), lane_shr1(v.w));
}
__device__ __forceinline__ float4 lane_shl1_4(float4 v) {
    return make_float4(lane_shl1(v.x), lane_shl1(v.y), lane_shl1(v.z), lane_shl1(v.w));
}
__device__ __forceinline__ float bcast(float x, int lane) {
    return __int_as_float(__builtin_amdgcn_readlane(__float_as_int(x), lane));
}

__global__ __launch_bounds__(256, 2) void boxfilter9(const float* __restrict__ in,
                                                     float* __restrict__ out) {
    const int t     = threadIdx.x;
    const int l     = t & 63;                       // lane
    const int wid   = t >> 6;                       // wave in block
    const int unit  = blockIdx.x * 4 + wid;         // img*NSTRIP + strip (wave-uniform)
    const int img   = unit >> 5;                    // / NSTRIP
    const int strip = unit & (NSTRIP - 1);

    const float* __restrict__ inp  = in  + (size_t)img * W * W;
    float* __restrict__       outp = out + (size_t)img * W * W;
    const int y0 = strip * RR;
    const int cA = l << 2;                          // group A: cols 4l..4l+3
    const int cB = 256 + (l << 2);                  // group B: cols 256+4l..

    // 9-wide horizontal running sum from prev/own/next float4
    auto hchain = [](float4 p, float4 v, float4 n) -> float4 {
        float sp = (p.x + p.y) + (p.z + p.w);
        float sv = (v.x + v.y) + (v.z + v.w);
        float4 h;
        h.x = (sp + sv) + n.x;
        h.y = h.x - p.x + n.y;
        h.z = h.y - p.y + n.z;
        h.w = h.z - p.z + n.w;
        return h;
    };

    // horizontal 9-sums for row y (branch-free: clamp row, 0/1 mask for pad rows)
    auto compute_h = [&](int y, float4& hA, float4& hB) {
        int yc = y < 0 ? 0 : (y > W - 1 ? W - 1 : y);
        float m = (y == yc) ? 1.0f : 0.0f;          // wave-uniform
        const float* row = inp + yc * W;
        float4 vA = mul4s(ld4(row + cA), m);
        float4 vB = mul4s(ld4(row + cB), m);
        float4 pA = lane_shr1_4(vA);                // lane0 -> 0 == image left edge
        float4 nA = lane_shl1_4(vA);                // lane63 needs vB@lane0 (seam)
        float4 pB = lane_shr1_4(vB);                // lane0 needs vA@lane63 (seam)
        float4 nB = lane_shl1_4(vB);                // lane63 -> 0 == image right edge
        // seam fixups via uniform broadcasts + per-lane select
        float a63x = bcast(vA.x, 63), a63y = bcast(vA.y, 63),
              a63z = bcast(vA.z, 63), a63w = bcast(vA.w, 63);
        float b0x  = bcast(vB.x, 0),  b0y  = bcast(vB.y, 0),
              b0z  = bcast(vB.z, 0),  b0w  = bcast(vB.w, 0);
        pB.x = (l == 0) ? a63x : pB.x;
        pB.y = (l == 0) ? a63y : pB.y;
        pB.z = (l == 0) ? a63z : pB.z;
        pB.w = (l == 0) ? a63w : pB.w;
        nA.x = (l == 63) ? b0x : nA.x;
        nA.y = (l == 63) ? b0y : nA.y;
        nA.z = (l == 63) ? b0z : nA.z;
        nA.w = (l == 63) ? b0w : nA.w;
        hA = hchain(pA, vA, nA);
        hB = hchain(pB, vB, nB);
    };

    // prologue: ring[k] = h(y0-4+k), k=0..7; vsum8 = sum of those 8 rows
    float4 ringA[8], ringB[8];
    float4 vsA = make_float4(0, 0, 0, 0), vsB = make_float4(0, 0, 0, 0);
    #pragma unroll
    for (int k = 0; k < 8; ++k) {
        compute_h(y0 - 4 + k, ringA[k], ringB[k]);
        vsA = add4(vsA, ringA[k]);
        vsB = add4(vsB, ringB[k]);
    }

    // main: out(y) = vsum8 + h(y+4); vsum8' = out - h(y-4); slot (i&7) is both
    // the departing h(y-4) and the landing spot for h(y+4) (read before write).
    #pragma unroll
    for (int i = 0; i < RR; ++i) {
        float4 hA, hB;
        compute_h(y0 + 4 + i, hA, hB);
        float4 oA = add4(vsA, hA);
        float4 oB = add4(vsB, hB);
        float* orow = outp + (size_t)(y0 + i) * W;
        st4_nt(orow + cA, oA);
        st4_nt(orow + cB, oB);
        vsA = sub4(oA, ringA[i & 7]);
        vsB = sub4(oB, ringB[i & 7]);
        ringA[i & 7] = hA;
        ringB[i & 7] = hB;
    }
}

extern "C" void kernel_launch(void* const* d_in, const int* in_sizes, int n_in,
                              void* d_out, int out_size, void* d_ws, size_t ws_size,
                              hipStream_t stream) {
    const float* x = (const float*)d_in[0];
    float* y = (float*)d_out;
    // 128 images x 32 strips = 4096 wave-units, 4 per 256-thread block
    dim3 grid(128 * NSTRIP / 4);
    dim3 block(256);
    boxfilter9<<<grid, block, 0, stream>>>(x, y);
}